// Round 6
// baseline (279.679 us; speedup 1.0000x reference)
//
#include <hip/hip_runtime.h>
#include <hip/hip_bf16.h>
#include <math.h>

#define B_ 4
#define N_ 4096
#define M_ 1024
#define C_ 384
#define NH_ 8
#define HD_ 48

typedef float f32x4 __attribute__((ext_vector_type(4)));
typedef short bf16x8 __attribute__((ext_vector_type(8)));

__device__ __forceinline__ unsigned short f2bf(float x) {  // RNE
    unsigned int u = __builtin_bit_cast(unsigned int, x);
    return (unsigned short)((u + 0x7FFFu + ((u >> 16) & 1u)) >> 16);
}
__device__ __forceinline__ unsigned short f2bf_trunc(float x) {
    return (unsigned short)(__builtin_bit_cast(unsigned int, x) >> 16);
}
__device__ __forceinline__ float bf2f(unsigned short x) {
    return __builtin_bit_cast(float, (unsigned int)x << 16);
}
__device__ __forceinline__ float fast_exp2(float x) {
#if __has_builtin(__builtin_amdgcn_exp2f)
    return __builtin_amdgcn_exp2f(x);
#else
    return exp2f(x);
#endif
}
__device__ __forceinline__ uint2 pack4_rne(float a, float b, float c, float d) {
    uint2 r;
    r.x = (unsigned int)f2bf(a) | ((unsigned int)f2bf(b) << 16);
    r.y = (unsigned int)f2bf(c) | ((unsigned int)f2bf(d) << 16);
    return r;
}
__device__ __forceinline__ bf16x8 cvt8(float4 a, float4 b) {
    uint2 lo = pack4_rne(a.x, a.y, a.z, a.w);
    uint2 hi = pack4_rne(b.x, b.y, b.z, b.w);
    union { uint4 u; bf16x8 v; } c;
    c.u.x = lo.x; c.u.y = lo.y; c.u.z = hi.x; c.u.w = hi.y;
    return c.v;
}

// 48^-0.5 * log2(e): softmax via 2^x
#define QSCALE 0.20823490983597203f

// ---------------------------------------------------------------------------
// Transpose + convert weights: W[k][n] fp32 -> Wt[n][k] bf16. 64x64 tiles.
// ---------------------------------------------------------------------------
__global__ __launch_bounds__(256)
void transpose_w3(const float* __restrict__ Wq, const float* __restrict__ Wkv,
                  const float* __restrict__ Wproj,
                  unsigned short* __restrict__ Wq_t, unsigned short* __restrict__ Wkv_t,
                  unsigned short* __restrict__ Wproj_t)
{
    __shared__ unsigned short T[64 * 72];
    const int tid = threadIdx.x;
    int bid = blockIdx.x;
    const float* W; unsigned short* Wt; int N, kt, nt;
    if (bid < 36)       { W = Wq;    Wt = Wq_t;    N = 384; kt = bid / 6;  nt = bid - kt * 6; }
    else if (bid < 108) { bid -= 36;  W = Wkv;   Wt = Wkv_t;   N = 768; kt = bid / 12; nt = bid - kt * 12; }
    else                { bid -= 108; W = Wproj; Wt = Wproj_t; N = 384; kt = bid / 6;  nt = bid - kt * 6; }
    const int k0 = kt * 64, n0 = nt * 64;

    #pragma unroll
    for (int it = 0; it < 4; ++it) {
        int k = it * 16 + (tid >> 4);
        int n4 = (tid & 15) * 4;
        float4 v = *(const float4*)&W[(size_t)(k0 + k) * N + n0 + n4];
        T[(n4 + 0) * 72 + k] = f2bf(v.x);
        T[(n4 + 1) * 72 + k] = f2bf(v.y);
        T[(n4 + 2) * 72 + k] = f2bf(v.z);
        T[(n4 + 3) * 72 + k] = f2bf(v.w);
    }
    __syncthreads();
    #pragma unroll
    for (int i = 0; i < 2; ++i) {
        int s = tid + 256 * i;
        int n = s >> 3, part = s & 7;
        *(uint4*)&Wt[(size_t)(n0 + n) * C_ + k0 + part * 8] = *(const uint4*)&T[n * 72 + part * 8];
    }
}

// ---------------------------------------------------------------------------
// Fused q-proj + kv-proj. 128x64 tile/block; W col-slice (64x384) staged to
// LDS once; A (fp32) streams from global, converted to bf16 in registers.
// Operand-swapped MFMA -> thread owns 4 consecutive output cols.
// blocks [0,768): q-proj  -> qres bf16 [B,N,384], qbf = Q*QSCALE [B,H,N,48]
// blocks [768,1152): kv-proj -> kbf [B,H,M,48], vbf = V^T [B,H,48,M]
// ---------------------------------------------------------------------------
__global__ __launch_bounds__(256)
void gemm_qkv(const float* __restrict__ qx, const float* __restrict__ kvx,
              const unsigned short* __restrict__ Wqt, const unsigned short* __restrict__ Wkvt,
              unsigned short* __restrict__ qbf, unsigned short* __restrict__ qres,
              unsigned short* __restrict__ kbf, unsigned short* __restrict__ vbf)
{
    __shared__ unsigned short Ws[64 * 392];
    const int tid = threadIdx.x;
    const int wave = tid >> 6;
    const int lane = tid & 63;
    const int ln = lane & 15;
    const int quad = lane >> 4;

    int bid = blockIdx.x;
    int mode, row0, col0;
    const float* A; const unsigned short* Wt;
    if (bid < 768) { mode = 0; int rb = bid / 6;  col0 = (bid - rb * 6) * 64;  row0 = rb * 128; A = qx;  Wt = Wqt; }
    else { bid -= 768; mode = 1; int rb = bid / 12; col0 = (bid - rb * 12) * 64; row0 = rb * 128; A = kvx; Wt = Wkvt; }

    for (int i = tid; i < 3072; i += 256) {
        int n = i / 48, part = i - n * 48;
        *(uint4*)&Ws[n * 392 + part * 8] = *(const uint4*)&Wt[(size_t)(col0 + n) * C_ + part * 8];
    }
    __syncthreads();

    f32x4 acc[2][4];
    #pragma unroll
    for (int rt = 0; rt < 2; ++rt)
        #pragma unroll
        for (int ct = 0; ct < 4; ++ct) acc[rt][ct] = (f32x4){0.f, 0.f, 0.f, 0.f};

    const float* ar0 = A + (size_t)(row0 + wave * 32 + ln) * C_;
    const float* ar1 = ar0 + 16 * C_;

    #pragma unroll
    for (int kc = 0; kc < 12; ++kc) {
        const int ko = kc * 32 + quad * 8;
        float4 x0 = *(const float4*)(ar0 + ko);
        float4 x1 = *(const float4*)(ar0 + ko + 4);
        float4 y0 = *(const float4*)(ar1 + ko);
        float4 y1 = *(const float4*)(ar1 + ko + 4);
        bf16x8 b0 = cvt8(x0, x1);
        bf16x8 b1 = cvt8(y0, y1);
        #pragma unroll
        for (int ct = 0; ct < 4; ++ct) {
            bf16x8 aw = *(const bf16x8*)&Ws[(ct * 16 + ln) * 392 + kc * 32 + quad * 8];
            acc[0][ct] = __builtin_amdgcn_mfma_f32_16x16x32_bf16(aw, b0, acc[0][ct], 0, 0, 0);
            acc[1][ct] = __builtin_amdgcn_mfma_f32_16x16x32_bf16(aw, b1, acc[1][ct], 0, 0, 0);
        }
    }

    #pragma unroll
    for (int rt = 0; rt < 2; ++rt) {
        int grow = row0 + wave * 32 + rt * 16 + ln;
        #pragma unroll
        for (int ct = 0; ct < 4; ++ct) {
            int gcb = col0 + ct * 16 + quad * 4;
            f32x4 v = acc[rt][ct];
            if (mode == 0) {
                *(uint2*)&qres[(size_t)grow * C_ + gcb] = pack4_rne(v[0], v[1], v[2], v[3]);
                int b = grow >> 12, n = grow & (N_ - 1);
                int h = gcb / HD_, d = gcb - h * HD_;
                *(uint2*)&qbf[(((size_t)(b * NH_ + h) * N_) + n) * HD_ + d] =
                    pack4_rne(v[0] * QSCALE, v[1] * QSCALE, v[2] * QSCALE, v[3] * QSCALE);
            } else {
                int b = grow >> 10, m = grow & (M_ - 1);
                if (col0 < C_) {
                    int h = gcb / HD_, d = gcb - h * HD_;
                    *(uint2*)&kbf[(((size_t)(b * NH_ + h) * M_) + m) * HD_ + d] =
                        pack4_rne(v[0], v[1], v[2], v[3]);
                } else {
                    int c2 = gcb - C_;
                    int h = c2 / HD_, d = c2 - h * HD_;
                    size_t base = ((size_t)(b * NH_ + h) * HD_ + d) * M_ + m;
                    #pragma unroll
                    for (int r = 0; r < 4; ++r) vbf[base + (size_t)r * M_] = f2bf(v[r]);
                }
            }
        }
    }
}

// ---------------------------------------------------------------------------
// Out-proj: out = qres + of @ Wproj + bias. A is bf16; same streaming design.
// ---------------------------------------------------------------------------
__global__ __launch_bounds__(256)
void gemm_out(const unsigned short* __restrict__ A, const unsigned short* __restrict__ Wt,
              float* __restrict__ out0,
              const unsigned short* __restrict__ addend, const float* __restrict__ bias)
{
    __shared__ unsigned short Ws[64 * 392];
    const int tid = threadIdx.x;
    const int wave = tid >> 6;
    const int lane = tid & 63;
    const int ln = lane & 15;
    const int quad = lane >> 4;
    const int row0 = blockIdx.x * 128;
    const int col0 = blockIdx.y * 64;

    for (int i = tid; i < 3072; i += 256) {
        int n = i / 48, part = i - n * 48;
        *(uint4*)&Ws[n * 392 + part * 8] = *(const uint4*)&Wt[(size_t)(col0 + n) * C_ + part * 8];
    }
    __syncthreads();

    f32x4 acc[2][4];
    #pragma unroll
    for (int rt = 0; rt < 2; ++rt)
        #pragma unroll
        for (int ct = 0; ct < 4; ++ct) acc[rt][ct] = (f32x4){0.f, 0.f, 0.f, 0.f};

    const unsigned short* ar0 = A + (size_t)(row0 + wave * 32 + ln) * C_;
    const unsigned short* ar1 = ar0 + 16 * C_;

    #pragma unroll
    for (int kc = 0; kc < 12; ++kc) {
        bf16x8 b0 = *(const bf16x8*)(ar0 + kc * 32 + quad * 8);
        bf16x8 b1 = *(const bf16x8*)(ar1 + kc * 32 + quad * 8);
        #pragma unroll
        for (int ct = 0; ct < 4; ++ct) {
            bf16x8 aw = *(const bf16x8*)&Ws[(ct * 16 + ln) * 392 + kc * 32 + quad * 8];
            acc[0][ct] = __builtin_amdgcn_mfma_f32_16x16x32_bf16(aw, b0, acc[0][ct], 0, 0, 0);
            acc[1][ct] = __builtin_amdgcn_mfma_f32_16x16x32_bf16(aw, b1, acc[1][ct], 0, 0, 0);
        }
    }

    #pragma unroll
    for (int rt = 0; rt < 2; ++rt) {
        int grow = row0 + wave * 32 + rt * 16 + ln;
        #pragma unroll
        for (int ct = 0; ct < 4; ++ct) {
            int gcb = col0 + ct * 16 + quad * 4;
            f32x4 v = acc[rt][ct];
            size_t idx = (size_t)grow * C_ + gcb;
            uint2 ad = *(const uint2*)&addend[idx];
            float4 bi = *(const float4*)&bias[gcb];
            float4 o;
            o.x = v[0] + bf2f((unsigned short)(ad.x & 0xFFFF)) + bi.x;
            o.y = v[1] + bf2f((unsigned short)(ad.x >> 16))    + bi.y;
            o.z = v[2] + bf2f((unsigned short)(ad.y & 0xFFFF)) + bi.z;
            o.w = v[3] + bf2f((unsigned short)(ad.y >> 16))    + bi.w;
            *(float4*)&out0[idx] = o;
        }
    }
}

// ---------------------------------------------------------------------------
// Barrier-free MFMA attention. 4 waves x 16 q-rows per block (64 rows),
// grid 2048 blocks -> ~24 waves/CU. K/V/Q frags direct from global.
// Per-wave P slice is double-buffered (mt&1) so successive iterations'
// LDS ops don't serialize (WAR removed) -> loop bodies can overlap.
// Row sums in registers; 2 shuffles at end.
// ---------------------------------------------------------------------------
__global__ __launch_bounds__(256, 6)
void attn_mfma(const unsigned short* __restrict__ qbf,
               const unsigned short* __restrict__ kbf,
               const unsigned short* __restrict__ vbf,
               unsigned short* __restrict__ of)
{
    __shared__ unsigned short P[4][2][16 * 72];   // [wave][buf][q][m]

    const int tid = threadIdx.x;
    const int wave = tid >> 6;
    const int lane = tid & 63;
    const int ln = lane & 15;
    const int quad = lane >> 4;
    const int bh = blockIdx.x;
    const int n0w = blockIdx.y * 64 + wave * 16;

    const bf16x8 zero8 = (bf16x8){0, 0, 0, 0, 0, 0, 0, 0};

    // Q B-op fragments: lane ln = q-row; chunk1 quads>=2 are the d=48..63 pad.
    const unsigned short* qp = qbf + ((size_t)bh * N_ + n0w + ln) * HD_;
    bf16x8 qb0 = *(const bf16x8*)(qp + quad * 8);
    bf16x8 qb1 = *(const bf16x8*)(qp + 32 + quad * 8);   // overread ok (next rows)
    if (quad >= 2) qb1 = zero8;

    f32x4 O[3];
    #pragma unroll
    for (int ot = 0; ot < 3; ++ot) O[ot] = (f32x4){0.f, 0.f, 0.f, 0.f};
    float rs = 0.f;

    const unsigned short* kb = kbf + (size_t)bh * M_ * HD_;
    const unsigned short* vb = vbf + (size_t)bh * HD_ * M_;

    for (int mt = 0; mt < M_ / 64; ++mt) {
        unsigned short* Pw = &P[wave][mt & 1][0];

        // ---- S' = K Q^T : thread holds m = t*16+quad*4+{0..3}, q = ln ----
        f32x4 S[4];
        #pragma unroll
        for (int t = 0; t < 4; ++t) S[t] = (f32x4){0.f, 0.f, 0.f, 0.f};
        #pragma unroll
        for (int t = 0; t < 4; ++t) {
            const unsigned short* kp = kb + (size_t)(mt * 64 + t * 16 + ln) * HD_;
            bf16x8 k0 = *(const bf16x8*)(kp + quad * 8);
            bf16x8 k1 = *(const bf16x8*)(kp + 32 + quad * 8);
            if (quad >= 2) k1 = zero8;
            S[t] = __builtin_amdgcn_mfma_f32_16x16x32_bf16(k0, qb0, S[t], 0, 0, 0);
            S[t] = __builtin_amdgcn_mfma_f32_16x16x32_bf16(k1, qb1, S[t], 0, 0, 0);
        }

        // ---- V loads early (independent of S/P chain) ----
        bf16x8 va[3][2];
        #pragma unroll
        for (int ot = 0; ot < 3; ++ot) {
            const unsigned short* vp = vb + (size_t)(ot * 16 + ln) * M_ + mt * 64;
            va[ot][0] = *(const bf16x8*)(vp + quad * 8);
            va[ot][1] = *(const bf16x8*)(vp + 32 + quad * 8);
        }

        // ---- P = exp2(S'); b64 writes (4 consecutive m per thread) ----
        #pragma unroll
        for (int t = 0; t < 4; ++t) {
            float p0 = fast_exp2(S[t][0]);
            float p1 = fast_exp2(S[t][1]);
            float p2 = fast_exp2(S[t][2]);
            float p3 = fast_exp2(S[t][3]);
            rs += (p0 + p1) + (p2 + p3);
            uint2 pk;
            pk.x = (unsigned int)f2bf_trunc(p0) | ((unsigned int)f2bf_trunc(p1) << 16);
            pk.y = (unsigned int)f2bf_trunc(p2) | ((unsigned int)f2bf_trunc(p3) << 16);
            *(uint2*)&Pw[ln * 72 + t * 16 + quad * 4] = pk;
        }

        // ---- P B-op frags; O' += V^T P^T ----
        const unsigned short* Pr = &Pw[ln * 72];
        bf16x8 pb0 = *(const bf16x8*)(Pr + quad * 8);
        bf16x8 pb1 = *(const bf16x8*)(Pr + 32 + quad * 8);
        #pragma unroll
        for (int ot = 0; ot < 3; ++ot) {
            O[ot] = __builtin_amdgcn_mfma_f32_16x16x32_bf16(va[ot][0], pb0, O[ot], 0, 0, 0);
            O[ot] = __builtin_amdgcn_mfma_f32_16x16x32_bf16(va[ot][1], pb1, O[ot], 0, 0, 0);
        }
    }

    // ---- l[q=ln]: reduce partial sums over quads ----
    float x = rs;
    x += __shfl_xor(x, 16);
    x += __shfl_xor(x, 32);
    const float inv = 1.0f / x;

    // ---- epilogue: thread owns 4 consecutive d at q-row n0w+ln ----
    const int b = bh >> 3, h = bh & 7;
    size_t grow = (size_t)b * N_ + n0w + ln;
    #pragma unroll
    for (int ot = 0; ot < 3; ++ot) {
        int gcol = h * HD_ + ot * 16 + quad * 4;
        *(uint2*)&of[grow * C_ + gcol] =
            pack4_rne(O[ot][0] * inv, O[ot][1] * inv, O[ot][2] * inv, O[ot][3] * inv);
    }
}

extern "C" void kernel_launch(void* const* d_in, const int* in_sizes, int n_in,
                              void* d_out, int out_size, void* d_ws, size_t ws_size,
                              hipStream_t stream) {
    const float* q_x   = (const float*)d_in[0];
    const float* kv_x  = (const float*)d_in[1];
    const float* Wq    = (const float*)d_in[2];
    const float* Wkv   = (const float*)d_in[3];
    const float* Wproj = (const float*)d_in[4];
    const float* bproj = (const float*)d_in[5];
    float* out = (float*)d_out;

    unsigned short* qbf     = (unsigned short*)d_ws;  // [B,H,N,48] scaled
    unsigned short* kbf     = qbf     + 6291456;      // [B,H,M,48]  (qbf overread spills here: ok)
    unsigned short* vbf     = kbf     + 1572864;      // [B,H,48,M]  (kbf overread spills here: ok)
    unsigned short* qres    = vbf     + 1572864;      // [B,N,384] bf16 residual
    unsigned short* of      = qres    + 6291456;      // [B,N,384] bf16 attn out
    unsigned short* Wq_t    = of      + 6291456;      // [384][384]
    unsigned short* Wkv_t   = Wq_t    + 147456;       // [768][384]
    unsigned short* Wproj_t = Wkv_t   + 294912;       // [384][384]

    dim3 blk(256);

    transpose_w3<<<dim3(144), blk, 0, stream>>>(Wq, Wkv, Wproj, Wq_t, Wkv_t, Wproj_t);

    // fused q-proj + kv-proj
    gemm_qkv<<<dim3(1152), blk, 0, stream>>>(
        q_x, kv_x, Wq_t, Wkv_t, qbf, qres, kbf, vbf);

    // attention: 2048 blocks of 64 q-rows
    attn_mfma<<<dim3(32, 64), blk, 0, stream>>>(qbf, kbf, vbf, of);

    // out = qres + of @ Wproj + bproj
    gemm_out<<<dim3(128, 6), blk, 0, stream>>>(
        of, Wproj_t, out, qres, bproj);
}

// Round 7
// 227.338 us; speedup vs baseline: 1.2302x; 1.2302x over previous
//
#include <hip/hip_runtime.h>
#include <hip/hip_bf16.h>
#include <math.h>

#define B_ 4
#define N_ 4096
#define M_ 1024
#define C_ 384
#define NH_ 8
#define HD_ 48

typedef float f32x4 __attribute__((ext_vector_type(4)));
typedef short bf16x8 __attribute__((ext_vector_type(8)));

__device__ __forceinline__ unsigned short f2bf(float x) {  // RNE
    unsigned int u = __builtin_bit_cast(unsigned int, x);
    return (unsigned short)((u + 0x7FFFu + ((u >> 16) & 1u)) >> 16);
}
__device__ __forceinline__ unsigned short f2bf_trunc(float x) {
    return (unsigned short)(__builtin_bit_cast(unsigned int, x) >> 16);
}
__device__ __forceinline__ float bf2f(unsigned short x) {
    return __builtin_bit_cast(float, (unsigned int)x << 16);
}
__device__ __forceinline__ float fast_exp2(float x) {
#if __has_builtin(__builtin_amdgcn_exp2f)
    return __builtin_amdgcn_exp2f(x);
#else
    return exp2f(x);
#endif
}
__device__ __forceinline__ uint2 pack4_rne(float a, float b, float c, float d) {
    uint2 r;
    r.x = (unsigned int)f2bf(a) | ((unsigned int)f2bf(b) << 16);
    r.y = (unsigned int)f2bf(c) | ((unsigned int)f2bf(d) << 16);
    return r;
}
__device__ __forceinline__ bf16x8 cvt8(float4 a, float4 b) {
    uint2 lo = pack4_rne(a.x, a.y, a.z, a.w);
    uint2 hi = pack4_rne(b.x, b.y, b.z, b.w);
    union { uint4 u; bf16x8 v; } c;
    c.u.x = lo.x; c.u.y = lo.y; c.u.z = hi.x; c.u.w = hi.y;
    return c.v;
}

// 48^-0.5 * log2(e): softmax via 2^x
#define QSCALE 0.20823490983597203f

// ---------------------------------------------------------------------------
// Transpose + convert weights: W[k][n] fp32 -> Wt[n][k] bf16. 64x64 tiles.
// ---------------------------------------------------------------------------
__global__ __launch_bounds__(256)
void transpose_w3(const float* __restrict__ Wq, const float* __restrict__ Wkv,
                  const float* __restrict__ Wproj,
                  unsigned short* __restrict__ Wq_t, unsigned short* __restrict__ Wkv_t,
                  unsigned short* __restrict__ Wproj_t)
{
    __shared__ unsigned short T[64 * 72];
    const int tid = threadIdx.x;
    int bid = blockIdx.x;
    const float* W; unsigned short* Wt; int N, kt, nt;
    if (bid < 36)       { W = Wq;    Wt = Wq_t;    N = 384; kt = bid / 6;  nt = bid - kt * 6; }
    else if (bid < 108) { bid -= 36;  W = Wkv;   Wt = Wkv_t;   N = 768; kt = bid / 12; nt = bid - kt * 12; }
    else                { bid -= 108; W = Wproj; Wt = Wproj_t; N = 384; kt = bid / 6;  nt = bid - kt * 6; }
    const int k0 = kt * 64, n0 = nt * 64;

    #pragma unroll
    for (int it = 0; it < 4; ++it) {
        int k = it * 16 + (tid >> 4);
        int n4 = (tid & 15) * 4;
        float4 v = *(const float4*)&W[(size_t)(k0 + k) * N + n0 + n4];
        T[(n4 + 0) * 72 + k] = f2bf(v.x);
        T[(n4 + 1) * 72 + k] = f2bf(v.y);
        T[(n4 + 2) * 72 + k] = f2bf(v.z);
        T[(n4 + 3) * 72 + k] = f2bf(v.w);
    }
    __syncthreads();
    #pragma unroll
    for (int i = 0; i < 2; ++i) {
        int s = tid + 256 * i;
        int n = s >> 3, part = s & 7;
        *(uint4*)&Wt[(size_t)(n0 + n) * C_ + k0 + part * 8] = *(const uint4*)&T[n * 72 + part * 8];
    }
}

// ---------------------------------------------------------------------------
// Streaming GEMM (no LDS, no barriers): wave = 16 A-rows x 192 out-cols.
// A (fp32) converted to bf16 fragments in registers (full k=384 resident);
// W fragments stream from global (L1/L2-hot); 12 independent acc chains.
// units [0,512): q-proj; units [512,768): kv-proj.
// ---------------------------------------------------------------------------
__global__ __launch_bounds__(256)
void gemm_qkv(const float* __restrict__ qx, const float* __restrict__ kvx,
              const unsigned short* __restrict__ Wqt, const unsigned short* __restrict__ Wkvt,
              unsigned short* __restrict__ qbf, unsigned short* __restrict__ qres,
              unsigned short* __restrict__ kbf, unsigned short* __restrict__ vbf)
{
    const int tid = threadIdx.x;
    const int wave = tid >> 6;
    const int lane = tid & 63;
    const int ln = lane & 15;
    const int quad = lane >> 4;

    int u = blockIdx.x;
    int mode, row, colbase;
    const float* A; const unsigned short* Wt;
    if (u < 512) { mode = 0; A = qx;  Wt = Wqt;  row = (u >> 1) * 64 + wave * 16 + ln; colbase = (u & 1) * 192; }
    else { u -= 512; mode = 1; A = kvx; Wt = Wkvt; row = (u >> 2) * 64 + wave * 16 + ln; colbase = (u & 3) * 192; }

    // A fragments: 16 rows x 384 k, this lane's share (12 chunks x 8 bf16)
    bf16x8 af[12];
    const float* ap = A + (size_t)row * C_ + quad * 8;
    #pragma unroll
    for (int kc = 0; kc < 12; ++kc) {
        float4 x0 = *(const float4*)(ap + kc * 32);
        float4 x1 = *(const float4*)(ap + kc * 32 + 4);
        af[kc] = cvt8(x0, x1);
    }

    f32x4 acc[12];
    #pragma unroll
    for (int ct = 0; ct < 12; ++ct) acc[ct] = (f32x4){0.f, 0.f, 0.f, 0.f};

    #pragma unroll
    for (int kc = 0; kc < 12; ++kc) {
        bf16x8 wf[12];
        #pragma unroll
        for (int ct = 0; ct < 12; ++ct)
            wf[ct] = *(const bf16x8*)&Wt[(size_t)(colbase + ct * 16 + ln) * C_ + kc * 32 + quad * 8];
        #pragma unroll
        for (int ct = 0; ct < 12; ++ct)
            acc[ct] = __builtin_amdgcn_mfma_f32_16x16x32_bf16(wf[ct], af[kc], acc[ct], 0, 0, 0);
    }

    // epilogue: thread owns row `row`, cols colbase+ct*16+quad*4 .. +3
    #pragma unroll
    for (int ct = 0; ct < 12; ++ct) {
        int col = colbase + ct * 16 + quad * 4;
        f32x4 v = acc[ct];
        if (mode == 0) {
            *(uint2*)&qres[(size_t)row * C_ + col] = pack4_rne(v[0], v[1], v[2], v[3]);
            int b = row >> 12, n = row & (N_ - 1);
            int h = col / HD_, d = col - h * HD_;
            *(uint2*)&qbf[(((size_t)(b * NH_ + h) * N_) + n) * HD_ + d] =
                pack4_rne(v[0] * QSCALE, v[1] * QSCALE, v[2] * QSCALE, v[3] * QSCALE);
        } else {
            int b = row >> 10, m = row & (M_ - 1);
            if (col < C_) {
                int h = col / HD_, d = col - h * HD_;
                *(uint2*)&kbf[(((size_t)(b * NH_ + h) * M_) + m) * HD_ + d] =
                    pack4_rne(v[0], v[1], v[2], v[3]);
            } else {
                int c2 = col - C_;
                int h = c2 / HD_, d = c2 - h * HD_;
                size_t base = ((size_t)(b * NH_ + h) * HD_ + d) * M_ + m;
                #pragma unroll
                for (int r = 0; r < 4; ++r) vbf[base + (size_t)r * M_] = f2bf(v[r]);
            }
        }
    }
}

// ---------------------------------------------------------------------------
// Streaming out-proj: out = qres + of @ Wproj + bias. Same structure, bf16 A.
// ---------------------------------------------------------------------------
__global__ __launch_bounds__(256)
void gemm_out(const unsigned short* __restrict__ A, const unsigned short* __restrict__ Wt,
              float* __restrict__ out0,
              const unsigned short* __restrict__ addend, const float* __restrict__ bias)
{
    const int tid = threadIdx.x;
    const int wave = tid >> 6;
    const int lane = tid & 63;
    const int ln = lane & 15;
    const int quad = lane >> 4;
    const int u = blockIdx.x;
    const int row = (u >> 1) * 64 + wave * 16 + ln;
    const int colbase = (u & 1) * 192;

    bf16x8 af[12];
    const unsigned short* ap = A + (size_t)row * C_ + quad * 8;
    #pragma unroll
    for (int kc = 0; kc < 12; ++kc)
        af[kc] = *(const bf16x8*)(ap + kc * 32);

    f32x4 acc[12];
    #pragma unroll
    for (int ct = 0; ct < 12; ++ct) acc[ct] = (f32x4){0.f, 0.f, 0.f, 0.f};

    #pragma unroll
    for (int kc = 0; kc < 12; ++kc) {
        bf16x8 wf[12];
        #pragma unroll
        for (int ct = 0; ct < 12; ++ct)
            wf[ct] = *(const bf16x8*)&Wt[(size_t)(colbase + ct * 16 + ln) * C_ + kc * 32 + quad * 8];
        #pragma unroll
        for (int ct = 0; ct < 12; ++ct)
            acc[ct] = __builtin_amdgcn_mfma_f32_16x16x32_bf16(wf[ct], af[kc], acc[ct], 0, 0, 0);
    }

    #pragma unroll
    for (int ct = 0; ct < 12; ++ct) {
        int col = colbase + ct * 16 + quad * 4;
        f32x4 v = acc[ct];
        size_t idx = (size_t)row * C_ + col;
        uint2 ad = *(const uint2*)&addend[idx];
        float4 bi = *(const float4*)&bias[col];
        float4 o;
        o.x = v[0] + bf2f((unsigned short)(ad.x & 0xFFFF)) + bi.x;
        o.y = v[1] + bf2f((unsigned short)(ad.x >> 16))    + bi.y;
        o.z = v[2] + bf2f((unsigned short)(ad.y & 0xFFFF)) + bi.z;
        o.w = v[3] + bf2f((unsigned short)(ad.y >> 16))    + bi.w;
        *(float4*)&out0[idx] = o;
    }
}

// ---------------------------------------------------------------------------
// Barrier-free MFMA attention, 64 q-rows per wave (4 q-tiles). Block = 4
// waves x 256 q-rows; grid (32 bh, 16) = 512 blocks = 2/CU. K/V fragments
// direct from global (L2-resident per XCD via bh%8 pinning); all 14 loads
// hoisted to iteration top. exp/P-write per K-tile keeps S liveness low.
// Per-wave P slice single-buffered (in-order DS pipe handles WAR).
// ---------------------------------------------------------------------------
__global__ __launch_bounds__(256, 2)
void attn_mfma(const unsigned short* __restrict__ qbf,
               const unsigned short* __restrict__ kbf,
               const unsigned short* __restrict__ vbf,
               unsigned short* __restrict__ of)
{
    __shared__ unsigned short P[4][64 * 72];   // per-wave [q][m], 36 KB total

    const int tid = threadIdx.x;
    const int wave = tid >> 6;
    const int lane = tid & 63;
    const int ln = lane & 15;
    const int quad = lane >> 4;
    const int bh = blockIdx.x;
    const int n0w = blockIdx.y * 256 + wave * 64;

    const bf16x8 zero8 = (bf16x8){0, 0, 0, 0, 0, 0, 0, 0};

    // Q B-op fragments, 4 q-tiles; chunk1 quads>=2 are the d=48..63 pad.
    bf16x8 qb[4][2];
    #pragma unroll
    for (int qt = 0; qt < 4; ++qt) {
        const unsigned short* qp = qbf + ((size_t)bh * N_ + n0w + qt * 16 + ln) * HD_;
        qb[qt][0] = *(const bf16x8*)(qp + quad * 8);
        qb[qt][1] = *(const bf16x8*)(qp + 32 + quad * 8);   // overread ok
        if (quad >= 2) qb[qt][1] = zero8;
    }

    f32x4 O[3][4];   // [d-tile][q-tile]
    #pragma unroll
    for (int ot = 0; ot < 3; ++ot)
        #pragma unroll
        for (int qt = 0; qt < 4; ++qt) O[ot][qt] = (f32x4){0.f, 0.f, 0.f, 0.f};
    float rs[4] = {0.f, 0.f, 0.f, 0.f};

    const unsigned short* kb = kbf + (size_t)bh * M_ * HD_;
    const unsigned short* vb = vbf + (size_t)bh * HD_ * M_;
    unsigned short* Pw = &P[wave][0];

    for (int mt = 0; mt < M_ / 64; ++mt) {
        // ---- hoist all 14 global loads (6 V + 8 K) ----
        bf16x8 va[3][2];
        #pragma unroll
        for (int ot = 0; ot < 3; ++ot) {
            const unsigned short* vp = vb + (size_t)(ot * 16 + ln) * M_ + mt * 64;
            va[ot][0] = *(const bf16x8*)(vp + quad * 8);
            va[ot][1] = *(const bf16x8*)(vp + 32 + quad * 8);
        }
        bf16x8 ka[4][2];
        #pragma unroll
        for (int t = 0; t < 4; ++t) {
            const unsigned short* kp = kb + (size_t)(mt * 64 + t * 16 + ln) * HD_;
            ka[t][0] = *(const bf16x8*)(kp + quad * 8);
            ka[t][1] = *(const bf16x8*)(kp + 32 + quad * 8);
            if (quad >= 2) ka[t][1] = zero8;
        }

        // ---- per K-tile: S' = K Q^T, exp, P-write (S liveness = 1 tile) ----
        #pragma unroll
        for (int t = 0; t < 4; ++t) {
            #pragma unroll
            for (int qt = 0; qt < 4; ++qt) {
                f32x4 s = (f32x4){0.f, 0.f, 0.f, 0.f};
                s = __builtin_amdgcn_mfma_f32_16x16x32_bf16(ka[t][0], qb[qt][0], s, 0, 0, 0);
                s = __builtin_amdgcn_mfma_f32_16x16x32_bf16(ka[t][1], qb[qt][1], s, 0, 0, 0);
                float p0 = fast_exp2(s[0]);
                float p1 = fast_exp2(s[1]);
                float p2 = fast_exp2(s[2]);
                float p3 = fast_exp2(s[3]);
                rs[qt] += (p0 + p1) + (p2 + p3);
                uint2 pk;
                pk.x = (unsigned int)f2bf_trunc(p0) | ((unsigned int)f2bf_trunc(p1) << 16);
                pk.y = (unsigned int)f2bf_trunc(p2) | ((unsigned int)f2bf_trunc(p3) << 16);
                *(uint2*)&Pw[(qt * 16 + ln) * 72 + t * 16 + quad * 4] = pk;
            }
        }

        // ---- PV: per q-tile read P B-frags, 6 MFMA ----
        #pragma unroll
        for (int qt = 0; qt < 4; ++qt) {
            const unsigned short* Pr = &Pw[(qt * 16 + ln) * 72];
            bf16x8 pb0 = *(const bf16x8*)(Pr + quad * 8);
            bf16x8 pb1 = *(const bf16x8*)(Pr + 32 + quad * 8);
            #pragma unroll
            for (int ot = 0; ot < 3; ++ot) {
                O[ot][qt] = __builtin_amdgcn_mfma_f32_16x16x32_bf16(va[ot][0], pb0, O[ot][qt], 0, 0, 0);
                O[ot][qt] = __builtin_amdgcn_mfma_f32_16x16x32_bf16(va[ot][1], pb1, O[ot][qt], 0, 0, 0);
            }
        }
    }

    // ---- l[q]: reduce partial sums over quads (each lane q = qt*16+ln) ----
    float inv[4];
    #pragma unroll
    for (int qt = 0; qt < 4; ++qt) {
        float x = rs[qt];
        x += __shfl_xor(x, 16);
        x += __shfl_xor(x, 32);
        inv[qt] = 1.0f / x;
    }

    // ---- epilogue: thread owns 4 consecutive d at q-row n0w+qt*16+ln ----
    const int b = bh >> 3, h = bh & 7;
    #pragma unroll
    for (int ot = 0; ot < 3; ++ot)
        #pragma unroll
        for (int qt = 0; qt < 4; ++qt) {
            size_t grow = (size_t)b * N_ + n0w + qt * 16 + ln;
            int gcol = h * HD_ + ot * 16 + quad * 4;
            *(uint2*)&of[grow * C_ + gcol] =
                pack4_rne(O[ot][qt][0] * inv[qt], O[ot][qt][1] * inv[qt],
                          O[ot][qt][2] * inv[qt], O[ot][qt][3] * inv[qt]);
        }
}

extern "C" void kernel_launch(void* const* d_in, const int* in_sizes, int n_in,
                              void* d_out, int out_size, void* d_ws, size_t ws_size,
                              hipStream_t stream) {
    const float* q_x   = (const float*)d_in[0];
    const float* kv_x  = (const float*)d_in[1];
    const float* Wq    = (const float*)d_in[2];
    const float* Wkv   = (const float*)d_in[3];
    const float* Wproj = (const float*)d_in[4];
    const float* bproj = (const float*)d_in[5];
    float* out = (float*)d_out;

    unsigned short* qbf     = (unsigned short*)d_ws;  // [B,H,N,48] scaled
    unsigned short* kbf     = qbf     + 6291456;      // [B,H,M,48]  (qbf overread spills here: ok)
    unsigned short* vbf     = kbf     + 1572864;      // [B,H,48,M]  (kbf overread spills here: ok)
    unsigned short* qres    = vbf     + 1572864;      // [B,N,384] bf16 residual
    unsigned short* of      = qres    + 6291456;      // [B,N,384] bf16 attn out
    unsigned short* Wq_t    = of      + 6291456;      // [384][384]
    unsigned short* Wkv_t   = Wq_t    + 147456;       // [768][384]
    unsigned short* Wproj_t = Wkv_t   + 294912;       // [384][384]

    dim3 blk(256);

    transpose_w3<<<dim3(144), blk, 0, stream>>>(Wq, Wkv, Wproj, Wq_t, Wkv_t, Wproj_t);

    // fused q-proj + kv-proj (streaming, LDS-free)
    gemm_qkv<<<dim3(768), blk, 0, stream>>>(
        q_x, kv_x, Wq_t, Wkv_t, qbf, qres, kbf, vbf);

    // attention: 512 blocks x 256 q-rows
    attn_mfma<<<dim3(32, 16), blk, 0, stream>>>(qbf, kbf, vbf, of);

    // out = qres + of @ Wproj + bproj (streaming)
    gemm_out<<<dim3(512), blk, 0, stream>>>(of, Wproj_t, out, qres, bproj);
}

// Round 8
// 170.758 us; speedup vs baseline: 1.6379x; 1.3313x over previous
//
#include <hip/hip_runtime.h>
#include <hip/hip_bf16.h>
#include <math.h>

#define B_ 4
#define N_ 4096
#define M_ 1024
#define C_ 384
#define NH_ 8
#define HD_ 48

typedef float f32x4 __attribute__((ext_vector_type(4)));
typedef short bf16x8 __attribute__((ext_vector_type(8)));

typedef __attribute__((address_space(3))) unsigned int lds_uint;
typedef const __attribute__((address_space(1))) unsigned int glob_uint;

__device__ __forceinline__ void gld_lds16(const void* g, void* l) {
    // async global->LDS, 16 B/lane; LDS dest = wave-uniform base + lane*16
    __builtin_amdgcn_global_load_lds((glob_uint*)g, (lds_uint*)l, 16, 0, 0);
}

__device__ __forceinline__ unsigned short f2bf(float x) {  // RNE
    unsigned int u = __builtin_bit_cast(unsigned int, x);
    return (unsigned short)((u + 0x7FFFu + ((u >> 16) & 1u)) >> 16);
}
__device__ __forceinline__ unsigned short f2bf_trunc(float x) {
    return (unsigned short)(__builtin_bit_cast(unsigned int, x) >> 16);
}
__device__ __forceinline__ float bf2f(unsigned short x) {
    return __builtin_bit_cast(float, (unsigned int)x << 16);
}
__device__ __forceinline__ float fast_exp2(float x) {
#if __has_builtin(__builtin_amdgcn_exp2f)
    return __builtin_amdgcn_exp2f(x);
#else
    return exp2f(x);
#endif
}
__device__ __forceinline__ uint2 pack4_rne(float a, float b, float c, float d) {
    uint2 r;
    r.x = (unsigned int)f2bf(a) | ((unsigned int)f2bf(b) << 16);
    r.y = (unsigned int)f2bf(c) | ((unsigned int)f2bf(d) << 16);
    return r;
}

// 48^-0.5 * log2(e): softmax via 2^x
#define QSCALE 0.20823490983597203f

// ---------------------------------------------------------------------------
// Convert activations fp32 -> bf16 (flat float4 grid; q_x then kv_x)
// ---------------------------------------------------------------------------
__global__ __launch_bounds__(256)
void conv_act(const float* __restrict__ a, unsigned short* __restrict__ da,
              const float* __restrict__ b, unsigned short* __restrict__ db)
{
    size_t i4 = (size_t)blockIdx.x * 256 + threadIdx.x;
    const float* src; unsigned short* dst;
    if (i4 < 1572864u) { src = a; dst = da; }
    else { src = b; dst = db; i4 -= 1572864u; }
    float4 v = *(const float4*)&src[i4 * 4];
    *(uint2*)&dst[i4 * 4] = pack4_rne(v.x, v.y, v.z, v.w);
}

// ---------------------------------------------------------------------------
// Transpose + convert weights: W[k][n] fp32 -> Wt[n][k] bf16. 64x64 tiles.
// ---------------------------------------------------------------------------
__global__ __launch_bounds__(256)
void transpose_w3(const float* __restrict__ Wq, const float* __restrict__ Wkv,
                  const float* __restrict__ Wproj,
                  unsigned short* __restrict__ Wq_t, unsigned short* __restrict__ Wkv_t,
                  unsigned short* __restrict__ Wproj_t)
{
    __shared__ unsigned short T[64 * 72];
    const int tid = threadIdx.x;
    int bid = blockIdx.x;
    const float* W; unsigned short* Wt; int N, kt, nt;
    if (bid < 36)       { W = Wq;    Wt = Wq_t;    N = 384; kt = bid / 6;  nt = bid - kt * 6; }
    else if (bid < 108) { bid -= 36;  W = Wkv;   Wt = Wkv_t;   N = 768; kt = bid / 12; nt = bid - kt * 12; }
    else                { bid -= 108; W = Wproj; Wt = Wproj_t; N = 384; kt = bid / 6;  nt = bid - kt * 6; }
    const int k0 = kt * 64, n0 = nt * 64;

    #pragma unroll
    for (int it = 0; it < 4; ++it) {
        int k = it * 16 + (tid >> 4);
        int n4 = (tid & 15) * 4;
        float4 v = *(const float4*)&W[(size_t)(k0 + k) * N + n0 + n4];
        T[(n4 + 0) * 72 + k] = f2bf(v.x);
        T[(n4 + 1) * 72 + k] = f2bf(v.y);
        T[(n4 + 2) * 72 + k] = f2bf(v.z);
        T[(n4 + 3) * 72 + k] = f2bf(v.w);
    }
    __syncthreads();
    #pragma unroll
    for (int i = 0; i < 2; ++i) {
        int s = tid + 256 * i;
        int n = s >> 3, part = s & 7;
        *(uint4*)&Wt[(size_t)(n0 + n) * C_ + k0 + part * 8] = *(const uint4*)&T[n * 72 + part * 8];
    }
}

// ---------------------------------------------------------------------------
// m97-style GEMM core: 128x128 tile, BK=64, global_load_lds staging with
// XOR-8 chunk swizzle (conflict-free ds_read_b128, no padding needed).
// Both operands are bf16 [row][384]. Operand-swapped MFMA: thread owns
// row = rowbase+rt*16+ln, cols = colbase+ct*16+quad*4+{0..3}.
// ---------------------------------------------------------------------------
// stage 128 rows x 64 cols from src (row stride 384 bf16) into 16 KB LDS.
// LDS slot (row, c) holds global chunk c ^ (row & 7).  (chunk = 16 B)
__device__ __forceinline__ void stage128(const unsigned short* src, unsigned short* lds,
                                         int kk, int tid) {
    #pragma unroll
    for (int r = 0; r < 4; ++r) {
        int off = r * 256 + tid;          // 16B-slot index 0..1023
        int row = off >> 3;
        int c = off & 7;
        int gc = c ^ (row & 7);
        gld_lds16(src + (size_t)row * C_ + kk + gc * 8, lds + (size_t)off * 8);
    }
}
__device__ __forceinline__ bf16x8 frag_ld(const unsigned short* lds, int row, int chunk) {
    return *(const bf16x8*)&lds[row * 64 + ((chunk ^ (row & 7)) << 3)];
}

#define GEMM_CORE(Aptr, Wptr)                                                        \
    f32x4 acc[4][4];                                                                 \
    _Pragma("unroll")                                                                \
    for (int rt = 0; rt < 4; ++rt)                                                   \
        _Pragma("unroll")                                                            \
        for (int ct = 0; ct < 4; ++ct) acc[rt][ct] = (f32x4){0.f, 0.f, 0.f, 0.f};    \
    const int wrow0 = (wave & 1) * 64;                                               \
    const int wcol0 = (wave >> 1) * 64;                                              \
    for (int kk = 0; kk < C_; kk += 64) {                                            \
        __syncthreads();                                                             \
        stage128(Aptr, As, kk, tid);                                                 \
        stage128(Wptr, Ws, kk, tid);                                                 \
        __syncthreads();                                                             \
        _Pragma("unroll")                                                            \
        for (int ks = 0; ks < 2; ++ks) {                                             \
            bf16x8 af[4], wf[4];                                                     \
            _Pragma("unroll")                                                        \
            for (int rt = 0; rt < 4; ++rt)                                           \
                af[rt] = frag_ld(As, wrow0 + rt * 16 + ln, ks * 4 + quad);           \
            _Pragma("unroll")                                                        \
            for (int ct = 0; ct < 4; ++ct)                                           \
                wf[ct] = frag_ld(Ws, wcol0 + ct * 16 + ln, ks * 4 + quad);           \
            _Pragma("unroll")                                                        \
            for (int rt = 0; rt < 4; ++rt)                                           \
                _Pragma("unroll")                                                    \
                for (int ct = 0; ct < 4; ++ct)                                       \
                    acc[rt][ct] = __builtin_amdgcn_mfma_f32_16x16x32_bf16(           \
                        wf[ct], af[rt], acc[rt][ct], 0, 0, 0);                       \
        }                                                                            \
    }

// ---------------------------------------------------------------------------
// Fused q-proj (blocks [0,384)) + kv-proj (blocks [384,576)).
// ---------------------------------------------------------------------------
__global__ __launch_bounds__(256)
void gemm_qkv(const unsigned short* __restrict__ qx, const unsigned short* __restrict__ kvx,
              const unsigned short* __restrict__ Wqt, const unsigned short* __restrict__ Wkvt,
              unsigned short* __restrict__ qbf, unsigned short* __restrict__ qres,
              unsigned short* __restrict__ kbf, unsigned short* __restrict__ vbf)
{
    __shared__ unsigned short As[128 * 64];
    __shared__ unsigned short Ws[128 * 64];
    const int tid = threadIdx.x;
    const int wave = tid >> 6;
    const int lane = tid & 63;
    const int ln = lane & 15;
    const int quad = lane >> 4;

    int bid = blockIdx.x;
    int mode, row0, col0;
    const unsigned short *A, *Wt;
    if (bid < 384) { mode = 0; A = qx;  Wt = Wqt;  row0 = (bid / 3) * 128; col0 = (bid % 3) * 128; }
    else { bid -= 384; mode = 1; A = kvx; Wt = Wkvt; row0 = (bid / 6) * 128; col0 = (bid % 6) * 128; }

    GEMM_CORE(A + (size_t)row0 * C_, Wt + (size_t)col0 * C_)

    #pragma unroll
    for (int rt = 0; rt < 4; ++rt) {
        int grow = row0 + wrow0 + rt * 16 + ln;
        #pragma unroll
        for (int ct = 0; ct < 4; ++ct) {
            int col = col0 + wcol0 + ct * 16 + quad * 4;
            f32x4 v = acc[rt][ct];
            if (mode == 0) {
                *(uint2*)&qres[(size_t)grow * C_ + col] = pack4_rne(v[0], v[1], v[2], v[3]);
                int b = grow >> 12, n = grow & (N_ - 1);
                int h = col / HD_, d = col - h * HD_;
                *(uint2*)&qbf[(((size_t)(b * NH_ + h) * N_) + n) * HD_ + d] =
                    pack4_rne(v[0] * QSCALE, v[1] * QSCALE, v[2] * QSCALE, v[3] * QSCALE);
            } else {
                int b = grow >> 10, m = grow & (M_ - 1);
                if (col < C_) {
                    int h = col / HD_, d = col - h * HD_;
                    *(uint2*)&kbf[(((size_t)(b * NH_ + h) * M_) + m) * HD_ + d] =
                        pack4_rne(v[0], v[1], v[2], v[3]);
                } else {
                    int c2 = col - C_;
                    int h = c2 / HD_, d = c2 - h * HD_;
                    size_t base = ((size_t)(b * NH_ + h) * HD_ + d) * M_ + m;
                    #pragma unroll
                    for (int r = 0; r < 4; ++r) vbf[base + (size_t)r * M_] = f2bf(v[r]);
                }
            }
        }
    }
}

// ---------------------------------------------------------------------------
// Out-proj: out = qres + of @ Wproj + bias. 384 blocks.
// ---------------------------------------------------------------------------
__global__ __launch_bounds__(256)
void gemm_out(const unsigned short* __restrict__ A, const unsigned short* __restrict__ Wt,
              float* __restrict__ out0,
              const unsigned short* __restrict__ addend, const float* __restrict__ bias)
{
    __shared__ unsigned short As[128 * 64];
    __shared__ unsigned short Ws[128 * 64];
    const int tid = threadIdx.x;
    const int wave = tid >> 6;
    const int lane = tid & 63;
    const int ln = lane & 15;
    const int quad = lane >> 4;
    const int row0 = (blockIdx.x / 3) * 128;
    const int col0 = (blockIdx.x % 3) * 128;

    GEMM_CORE(A + (size_t)row0 * C_, Wt + (size_t)col0 * C_)

    #pragma unroll
    for (int rt = 0; rt < 4; ++rt) {
        int grow = row0 + wrow0 + rt * 16 + ln;
        #pragma unroll
        for (int ct = 0; ct < 4; ++ct) {
            int col = col0 + wcol0 + ct * 16 + quad * 4;
            f32x4 v = acc[rt][ct];
            size_t idx = (size_t)grow * C_ + col;
            uint2 ad = *(const uint2*)&addend[idx];
            float4 bi = *(const float4*)&bias[col];
            float4 o;
            o.x = v[0] + bf2f((unsigned short)(ad.x & 0xFFFF)) + bi.x;
            o.y = v[1] + bf2f((unsigned short)(ad.x >> 16))    + bi.y;
            o.z = v[2] + bf2f((unsigned short)(ad.y & 0xFFFF)) + bi.z;
            o.w = v[3] + bf2f((unsigned short)(ad.y >> 16))    + bi.w;
            *(float4*)&out0[idx] = o;
        }
    }
}

// ---------------------------------------------------------------------------
// Barrier-free MFMA attention, 64 q-rows per wave (4 q-tiles). Block = 4
// waves x 256 q-rows; grid (32 bh, 16) = 512 blocks. K/V fragments direct
// from global (L2-resident per XCD via bh%8 pinning).  [R6 version]
// ---------------------------------------------------------------------------
__global__ __launch_bounds__(256, 2)
void attn_mfma(const unsigned short* __restrict__ qbf,
               const unsigned short* __restrict__ kbf,
               const unsigned short* __restrict__ vbf,
               unsigned short* __restrict__ of)
{
    __shared__ unsigned short P[4][64 * 72];   // per-wave [q][m]

    const int tid = threadIdx.x;
    const int wave = tid >> 6;
    const int lane = tid & 63;
    const int ln = lane & 15;
    const int quad = lane >> 4;
    const int bh = blockIdx.x;
    const int n0w = blockIdx.y * 256 + wave * 64;

    const bf16x8 zero8 = (bf16x8){0, 0, 0, 0, 0, 0, 0, 0};

    bf16x8 qb[4][2];
    #pragma unroll
    for (int qt = 0; qt < 4; ++qt) {
        const unsigned short* qp = qbf + ((size_t)bh * N_ + n0w + qt * 16 + ln) * HD_;
        qb[qt][0] = *(const bf16x8*)(qp + quad * 8);
        qb[qt][1] = *(const bf16x8*)(qp + 32 + quad * 8);   // overread ok
        if (quad >= 2) qb[qt][1] = zero8;
    }

    f32x4 O[3][4];
    #pragma unroll
    for (int ot = 0; ot < 3; ++ot)
        #pragma unroll
        for (int qt = 0; qt < 4; ++qt) O[ot][qt] = (f32x4){0.f, 0.f, 0.f, 0.f};
    float rs[4] = {0.f, 0.f, 0.f, 0.f};

    const unsigned short* kb = kbf + (size_t)bh * M_ * HD_;
    const unsigned short* vb = vbf + (size_t)bh * HD_ * M_;
    unsigned short* Pw = &P[wave][0];

    for (int mt = 0; mt < M_ / 64; ++mt) {
        bf16x8 va[3][2];
        #pragma unroll
        for (int ot = 0; ot < 3; ++ot) {
            const unsigned short* vp = vb + (size_t)(ot * 16 + ln) * M_ + mt * 64;
            va[ot][0] = *(const bf16x8*)(vp + quad * 8);
            va[ot][1] = *(const bf16x8*)(vp + 32 + quad * 8);
        }
        bf16x8 ka[4][2];
        #pragma unroll
        for (int t = 0; t < 4; ++t) {
            const unsigned short* kp = kb + (size_t)(mt * 64 + t * 16 + ln) * HD_;
            ka[t][0] = *(const bf16x8*)(kp + quad * 8);
            ka[t][1] = *(const bf16x8*)(kp + 32 + quad * 8);
            if (quad >= 2) ka[t][1] = zero8;
        }

        #pragma unroll
        for (int t = 0; t < 4; ++t) {
            #pragma unroll
            for (int qt = 0; qt < 4; ++qt) {
                f32x4 s = (f32x4){0.f, 0.f, 0.f, 0.f};
                s = __builtin_amdgcn_mfma_f32_16x16x32_bf16(ka[t][0], qb[qt][0], s, 0, 0, 0);
                s = __builtin_amdgcn_mfma_f32_16x16x32_bf16(ka[t][1], qb[qt][1], s, 0, 0, 0);
                float p0 = fast_exp2(s[0]);
                float p1 = fast_exp2(s[1]);
                float p2 = fast_exp2(s[2]);
                float p3 = fast_exp2(s[3]);
                rs[qt] += (p0 + p1) + (p2 + p3);
                uint2 pk;
                pk.x = (unsigned int)f2bf_trunc(p0) | ((unsigned int)f2bf_trunc(p1) << 16);
                pk.y = (unsigned int)f2bf_trunc(p2) | ((unsigned int)f2bf_trunc(p3) << 16);
                *(uint2*)&Pw[(qt * 16 + ln) * 72 + t * 16 + quad * 4] = pk;
            }
        }

        #pragma unroll
        for (int qt = 0; qt < 4; ++qt) {
            const unsigned short* Pr = &Pw[(qt * 16 + ln) * 72];
            bf16x8 pb0 = *(const bf16x8*)(Pr + quad * 8);
            bf16x8 pb1 = *(const bf16x8*)(Pr + 32 + quad * 8);
            #pragma unroll
            for (int ot = 0; ot < 3; ++ot) {
                O[ot][qt] = __builtin_amdgcn_mfma_f32_16x16x32_bf16(va[ot][0], pb0, O[ot][qt], 0, 0, 0);
                O[ot][qt] = __builtin_amdgcn_mfma_f32_16x16x32_bf16(va[ot][1], pb1, O[ot][qt], 0, 0, 0);
            }
        }
    }

    float inv[4];
    #pragma unroll
    for (int qt = 0; qt < 4; ++qt) {
        float x = rs[qt];
        x += __shfl_xor(x, 16);
        x += __shfl_xor(x, 32);
        inv[qt] = 1.0f / x;
    }

    const int b = bh >> 3, h = bh & 7;
    #pragma unroll
    for (int ot = 0; ot < 3; ++ot)
        #pragma unroll
        for (int qt = 0; qt < 4; ++qt) {
            size_t grow = (size_t)b * N_ + n0w + qt * 16 + ln;
            int gcol = h * HD_ + ot * 16 + quad * 4;
            *(uint2*)&of[grow * C_ + gcol] =
                pack4_rne(O[ot][qt][0] * inv[qt], O[ot][qt][1] * inv[qt],
                          O[ot][qt][2] * inv[qt], O[ot][qt][3] * inv[qt]);
        }
}

extern "C" void kernel_launch(void* const* d_in, const int* in_sizes, int n_in,
                              void* d_out, int out_size, void* d_ws, size_t ws_size,
                              hipStream_t stream) {
    const float* q_x   = (const float*)d_in[0];
    const float* kv_x  = (const float*)d_in[1];
    const float* Wq    = (const float*)d_in[2];
    const float* Wkv   = (const float*)d_in[3];
    const float* Wproj = (const float*)d_in[4];
    const float* bproj = (const float*)d_in[5];
    float* out = (float*)d_out;

    unsigned short* qbf     = (unsigned short*)d_ws;  // [B,H,N,48] scaled
    unsigned short* kbf     = qbf     + 6291456;      // [B,H,M,48]
    unsigned short* vbf     = kbf     + 1572864;      // [B,H,48,M]
    unsigned short* qres    = vbf     + 1572864;      // [B,N,384] bf16 residual
    unsigned short* of      = qres    + 6291456;      // [B,N,384] bf16 attn out
    unsigned short* qx_bf   = of      + 6291456;      // [B,N,384] bf16
    unsigned short* kvx_bf  = qx_bf   + 6291456;      // [B,M,384] bf16
    unsigned short* Wq_t    = kvx_bf  + 1572864;      // [384][384]
    unsigned short* Wkv_t   = Wq_t    + 147456;       // [768][384]
    unsigned short* Wproj_t = Wkv_t   + 294912;       // [384][384]

    dim3 blk(256);

    conv_act<<<dim3(7680), blk, 0, stream>>>(q_x, qx_bf, kv_x, kvx_bf);
    transpose_w3<<<dim3(144), blk, 0, stream>>>(Wq, Wkv, Wproj, Wq_t, Wkv_t, Wproj_t);

    // fused q-proj + kv-proj (m97-style, global_load_lds staging)
    gemm_qkv<<<dim3(576), blk, 0, stream>>>(
        qx_bf, kvx_bf, Wq_t, Wkv_t, qbf, qres, kbf, vbf);

    // attention: 512 blocks x 256 q-rows
    attn_mfma<<<dim3(32, 16), blk, 0, stream>>>(qbf, kbf, vbf, of);

    // out = qres + of @ Wproj + bproj
    gemm_out<<<dim3(384), blk, 0, stream>>>(of, Wproj_t, out, qres, bproj);
}